// Round 10
// baseline (57.191 us; speedup 1.0000x reference)
//
#include <hip/hip_runtime.h>

#define NTHR 512
#define NROW 5000
#define NB1 2503
#define NB2 1255
#define NB3 631
#define NB4 319

#define NQ_PHYS 625  // 5000 outputs / 8 per thread-iter
#define NQ_IDEN 625
#define NQ_R2 157    // 1256 r2 floats / 8

// db4 filters (exact values from reference)
__device__ __constant__ float DEC_LO[8] = {
    -0.010597401784997278f, 0.032883011666982945f, 0.030841381835986965f,
    -0.18703481171888114f, -0.02798376941698385f, 0.6308807679295904f,
    0.7148465705525415f, 0.23037781330885523f};
__device__ __constant__ float DEC_HI[8] = {
    -0.23037781330885523f, 0.7148465705525415f, -0.6308807679295904f,
    -0.02798376941698385f, 0.18703481171888114f, 0.030841381835986965f,
    -0.032883011666982945f, -0.010597401784997278f};
__device__ __constant__ float REC_LO[8] = {
    0.23037781330885523f, 0.7148465705525415f, 0.6308807679295904f,
    -0.02798376941698385f, -0.18703481171888114f, 0.030841381835986965f,
    0.032883011666982945f, -0.010597401784997278f};
__device__ __constant__ float REC_HI[8] = {
    -0.010597401784997278f, -0.032883011666982945f, 0.030841381835986965f,
    0.18703481171888114f, -0.02798376941698385f, -0.6308807679295904f,
    0.7148465705525415f, -0.23037781330885523f};

// ---------------- decomposition (unchanged from round-5 kernel) ----------------

__device__ __forceinline__ void dwt_accum2(const float v[10], float& sa0, float& sd0,
                                           float& sa1, float& sd1) {
  sa0 = sd0 = sa1 = sd1 = 0.f;
#pragma unroll
  for (int j = 0; j < 8; ++j) {
    const float lo = DEC_LO[7 - j], hi = DEC_HI[7 - j];
    sa0 = fmaf(lo, v[j], sa0);
    sd0 = fmaf(hi, v[j], sd0);
    sa1 = fmaf(lo, v[j + 2], sa1);
    sd1 = fmaf(hi, v[j + 2], sd1);
  }
}

__device__ __forceinline__ void dwt_glob(const float* __restrict__ x, int n, int n_out,
                                         float* __restrict__ oa, float* __restrict__ od,
                                         int tid) {
  const int npair = (n_out + 1) / 2;
  for (int t = tid; t < npair; t += NTHR) {
    const int i0 = 2 * t;
    float v[10];
    if (i0 >= 3 && 2 * i0 + 4 <= n) {
      const float2* s2 = reinterpret_cast<const float2*>(x + 2 * i0 - 6);
#pragma unroll
      for (int j = 0; j < 5; ++j) {
        const float2 p = s2[j];
        v[2 * j] = p.x;
        v[2 * j + 1] = p.y;
      }
    } else {
#pragma unroll
      for (int j = 0; j < 10; ++j) {
        const int p = 2 * i0 + j;
        const int q = (p < 6) ? (5 - p) : ((p < n + 6) ? (p - 6) : (2 * n + 5 - p));
        v[j] = x[q];
      }
    }
    float sa0, sd0, sa1, sd1;
    dwt_accum2(v, sa0, sd0, sa1, sd1);
    if (i0 + 1 < n_out) {
      *reinterpret_cast<float2*>(oa + i0) = make_float2(sa0, sa1);
      *reinterpret_cast<float2*>(od + i0) = make_float2(sd0, sd1);
    } else {
      oa[i0] = sa0;
      od[i0] = sd0;
    }
  }
}

__device__ __forceinline__ void dwt_step(const float* __restrict__ src, int n, int n_out,
                                         float* __restrict__ oa, float* __restrict__ od,
                                         int tid) {
  const int npair = (n_out + 1) / 2;
  for (int t = tid; t < npair; t += NTHR) {
    const int i0 = 2 * t;
    float v[10];
    if (i0 >= 3 && 2 * i0 + 4 <= n) {
      const float2* s2 = reinterpret_cast<const float2*>(src + 2 * i0 - 6);
#pragma unroll
      for (int j = 0; j < 5; ++j) {
        const float2 p = s2[j];
        v[2 * j] = p.x;
        v[2 * j + 1] = p.y;
      }
    } else {
#pragma unroll
      for (int j = 0; j < 10; ++j) {
        const int p = 2 * i0 + j;
        const int q = (p < 6) ? (5 - p) : ((p < n + 6) ? (p - 6) : (2 * n + 5 - p));
        v[j] = src[q];
      }
    }
    float sa0, sd0, sa1, sd1;
    dwt_accum2(v, sa0, sd0, sa1, sd1);
    if (i0 + 1 < n_out) {
      *reinterpret_cast<float2*>(oa + i0) = make_float2(sa0, sa1);
      *reinterpret_cast<float2*>(od + i0) = make_float2(sd0, sd1);
    } else {
      oa[i0] = sa0;
      od[i0] = sd0;
    }
  }
}

// ---------------- fused reconstruction ----------------

// load 7 consecutive floats starting at even LDS index
__device__ __forceinline__ void load7(const float* __restrict__ p, float w[7]) {
  const float2 w0 = *reinterpret_cast<const float2*>(p);
  const float2 w1 = *reinterpret_cast<const float2*>(p + 2);
  const float2 w2 = *reinterpret_cast<const float2*>(p + 4);
  w[0] = w0.x; w[1] = w0.y; w[2] = w1.x; w[3] = w1.y; w[4] = w2.x; w[5] = w2.y;
  w[6] = p[6];
}

// 8 upsampled values r[0..7] = idwt outputs 2i,2i+1 for i=k (k=0..3) from
// window(s) w*[k..k+3]; accumulation order matches the original idwt pair
// (per tap s: CA contribution then CD contribution) for bitwise identity.
__device__ __forceinline__ void up_lo(const float w[7], float r[8]) {
#pragma unroll
  for (int k = 0; k < 4; ++k) {
    float e = 0.f, o = 0.f;
#pragma unroll
    for (int s = 0; s < 4; ++s) {
      const float c = w[k + 3 - s];
      e = fmaf(REC_LO[2 * s], c, e);
      o = fmaf(REC_LO[2 * s + 1], c, o);
    }
    r[2 * k] = e;
    r[2 * k + 1] = o;
  }
}

__device__ __forceinline__ void up_hi(const float w[7], float r[8]) {
#pragma unroll
  for (int k = 0; k < 4; ++k) {
    float e = 0.f, o = 0.f;
#pragma unroll
    for (int s = 0; s < 4; ++s) {
      const float c = w[k + 3 - s];
      e = fmaf(REC_HI[2 * s], c, e);
      o = fmaf(REC_HI[2 * s + 1], c, o);
    }
    r[2 * k] = e;
    r[2 * k + 1] = o;
  }
}

__device__ __forceinline__ void up_both(const float wa[7], const float wd[7], float r[8]) {
#pragma unroll
  for (int k = 0; k < 4; ++k) {
    float e = 0.f, o = 0.f;
#pragma unroll
    for (int s = 0; s < 4; ++s) {
      const float a = wa[k + 3 - s], d = wd[k + 3 - s];
      e = fmaf(REC_LO[2 * s], a, e);
      o = fmaf(REC_LO[2 * s + 1], a, o);
      e = fmaf(REC_HI[2 * s], d, e);
      o = fmaf(REC_HI[2 * s + 1], d, o);
    }
    r[2 * k] = e;
    r[2 * k + 1] = o;
  }
}

// one idwt output pair from register windows a[0..4] / d[0..4]
template <bool CA, bool CD>
__device__ __forceinline__ float4 pair_eo(const float* a, const float* d) {
  float e0 = 0.f, o0 = 0.f, e1 = 0.f, o1 = 0.f;
#pragma unroll
  for (int s = 0; s < 4; ++s) {
    const float rl0 = REC_LO[2 * s], rl1 = REC_LO[2 * s + 1];
    const float rh0 = REC_HI[2 * s], rh1 = REC_HI[2 * s + 1];
    if (CA) {
      e0 = fmaf(rl0, a[3 - s], e0);
      o0 = fmaf(rl1, a[3 - s], o0);
      e1 = fmaf(rl0, a[4 - s], e1);
      o1 = fmaf(rl1, a[4 - s], o1);
    }
    if (CD) {
      e0 = fmaf(rh0, d[3 - s], e0);
      o0 = fmaf(rh1, d[3 - s], o0);
      e1 = fmaf(rh0, d[4 - s], e1);
      o1 = fmaf(rh1, d[4 - s], o1);
    }
  }
  return make_float4(e0, o0, e1, o1);
}

// r3 = idwt(a4,d4) in registers, then r2 = idwt(r3,d3) -> C
__device__ __forceinline__ void r2_fused(const float* __restrict__ a4,
                                         const float* __restrict__ d4,
                                         const float* __restrict__ d3,
                                         float* __restrict__ r2out, int tid) {
  float4* out4 = reinterpret_cast<float4*>(r2out);
  for (int t = tid; t < NQ_R2; t += NTHR) {
    float wa[7], wd[7], w3[7];
    load7(a4 + 2 * t, wa);
    load7(d4 + 2 * t, wd);
    load7(d3 + 4 * t, w3);
    float r3v[8];
    up_both(wa, wd, r3v);
    out4[2 * t] = pair_eo<true, true>(r3v, w3);
    out4[2 * t + 1] = pair_eo<true, true>(r3v + 2, w3 + 2);
  }
}

// r1 = idwt(r2,0) in registers, then physio = idwt(r1,0) -> global
__device__ __forceinline__ void physio_fused(const float* __restrict__ r2,
                                             float* __restrict__ out, int tid) {
  float4* out4 = reinterpret_cast<float4*>(out);
  for (int t = tid; t < NQ_PHYS; t += NTHR) {
    float w[7];
    load7(r2 + 2 * t, w);
    float r1v[8];
    up_lo(w, r1v);
    out4[2 * t] = pair_eo<true, false>(r1v, nullptr);
    out4[2 * t + 1] = pair_eo<true, false>(r1v + 2, nullptr);
  }
}

// s1 = idwt(0,d2) in registers, then identity = idwt(s1,d1) -> global
__device__ __forceinline__ void identity_fused(const float* __restrict__ d2,
                                               const float* __restrict__ d1,
                                               float* __restrict__ out, int tid) {
  float4* out4 = reinterpret_cast<float4*>(out);
  for (int t = tid; t < NQ_IDEN; t += NTHR) {
    float w2[7], w1[7];
    load7(d2 + 2 * t, w2);
    load7(d1 + 4 * t, w1);
    float s1v[8];
    up_hi(w2, s1v);
    out4[2 * t] = pair_eo<true, true>(s1v, w1);
    out4[2 * t + 1] = pair_eo<true, true>(s1v + 2, w1 + 2);
  }
}

__global__ __launch_bounds__(NTHR, 8) void wavelet_kernel(
    const float* __restrict__ x, float* __restrict__ out_physio,
    float* __restrict__ out_identity) {
  // Aliased LDS: 7520 floats = 30,080 B -> 4 blocks/CU at 512 thr (wave cap 32/CU)
  // A: a1 -> {a3@0, d3@+632, a4@+1264, d4@+1584}
  // B: d1 (live to end);  C: a2 -> r2;  D: d2 (live to end)
  __shared__ __align__(16) float A[2504];
  __shared__ __align__(16) float B[2504];
  __shared__ __align__(16) float C[1256];
  __shared__ __align__(16) float D[1256];

  float* const a3 = A;         // 631 @ A[0..630]
  float* const d3 = A + 632;   // 631 @ A[632..1262]
  float* const a4 = A + 1264;  // 319
  float* const d4 = A + 1584;  // 319 (ends 1902 < 2504)

  const int b = blockIdx.x;
  const int tid = threadIdx.x;
  const float* xrow = x + (size_t)b * NROW;

  // decomposition (level 1 straight from global; x row is L1/L2-resident)
  dwt_glob(xrow, NROW, NB1, A, B, tid);  // a1 -> A, d1 -> B
  __syncthreads();
  dwt_step(A, NB1, NB2, C, D, tid);      // a2 -> C, d2 -> D
  __syncthreads();
  dwt_step(C, NB2, NB3, a3, d3, tid);    // a1 dead: a3/d3 into A
  __syncthreads();
  dwt_step(a3, NB3, NB4, a4, d4, tid);   // reads A[0..630], writes A[1264..] disjoint
  __syncthreads();

  // reconstruction, fused: r3 and r1/s1 never touch LDS
  r2_fused(a4, d4, d3, C, tid);          // r2 -> C (a2 dead)
  __syncthreads();
  physio_fused(C, out_physio + (size_t)b * NROW, tid);
  identity_fused(D, B, out_identity + (size_t)b * NROW, tid);  // no barrier needed:
  // reads D (written 3 barriers ago) and B (4 barriers ago), disjoint from C
}

extern "C" void kernel_launch(void* const* d_in, const int* in_sizes, int n_in,
                              void* d_out, int out_size, void* d_ws, size_t ws_size,
                              hipStream_t stream) {
  const float* x = (const float*)d_in[0];
  float* out = (float*)d_out;
  const int B = in_sizes[0] / NROW;  // 4096
  wavelet_kernel<<<dim3(B), dim3(NTHR), 0, stream>>>(x, out, out + (size_t)B * NROW);
}

// Round 11
// 47.986 us; speedup vs baseline: 1.1918x; 1.1918x over previous
//
#include <hip/hip_runtime.h>

#define NTHR 512
#define NROW 5000
#define NB1 2503
#define NB2 1255
#define NB3 631
#define NB4 319

// db4 filters (exact values from reference)
__device__ __constant__ float DEC_LO[8] = {
    -0.010597401784997278f, 0.032883011666982945f, 0.030841381835986965f,
    -0.18703481171888114f, -0.02798376941698385f, 0.6308807679295904f,
    0.7148465705525415f, 0.23037781330885523f};
__device__ __constant__ float DEC_HI[8] = {
    -0.23037781330885523f, 0.7148465705525415f, -0.6308807679295904f,
    -0.02798376941698385f, 0.18703481171888114f, 0.030841381835986965f,
    -0.032883011666982945f, -0.010597401784997278f};
__device__ __constant__ float REC_LO[8] = {
    0.23037781330885523f, 0.7148465705525415f, 0.6308807679295904f,
    -0.02798376941698385f, -0.18703481171888114f, 0.030841381835986965f,
    0.032883011666982945f, -0.010597401784997278f};
__device__ __constant__ float REC_HI[8] = {
    -0.010597401784997278f, -0.032883011666982945f, 0.030841381835986965f,
    0.18703481171888114f, -0.02798376941698385f, -0.6308807679295904f,
    0.7148465705525415f, -0.23037781330885523f};

// two adjacent dwt outputs (i0, i0+1) from v[0..9] (taps p = 2*i0 + j)
__device__ __forceinline__ void dwt_accum2(const float v[10], float& sa0, float& sd0,
                                           float& sa1, float& sd1) {
  sa0 = sd0 = sa1 = sd1 = 0.f;
#pragma unroll
  for (int j = 0; j < 8; ++j) {
    const float lo = DEC_LO[7 - j], hi = DEC_HI[7 - j];
    sa0 = fmaf(lo, v[j], sa0);
    sd0 = fmaf(hi, v[j], sd0);
    sa1 = fmaf(lo, v[j + 2], sa1);
    sd1 = fmaf(hi, v[j + 2], sd1);
  }
}

// level-1 DWT reading x from GLOBAL, 2 outputs/thread
__device__ __forceinline__ void dwt_glob(const float* __restrict__ x, int n, int n_out,
                                         float* __restrict__ oa, float* __restrict__ od,
                                         int tid) {
  const int npair = (n_out + 1) / 2;
  for (int t = tid; t < npair; t += NTHR) {
    const int i0 = 2 * t;
    float v[10];
    if (i0 >= 3 && 2 * i0 + 4 <= n) {
      // taps x[2i0-6 .. 2i0+3], interior; 2i0-6 even -> 8B aligned
      const float2* s2 = reinterpret_cast<const float2*>(x + 2 * i0 - 6);
#pragma unroll
      for (int j = 0; j < 5; ++j) {
        const float2 p = s2[j];
        v[2 * j] = p.x;
        v[2 * j + 1] = p.y;
      }
    } else {
#pragma unroll
      for (int j = 0; j < 10; ++j) {
        const int p = 2 * i0 + j;
        const int q = (p < 6) ? (5 - p) : ((p < n + 6) ? (p - 6) : (2 * n + 5 - p));
        v[j] = x[q];
      }
    }
    float sa0, sd0, sa1, sd1;
    dwt_accum2(v, sa0, sd0, sa1, sd1);
    if (i0 + 1 < n_out) {
      *reinterpret_cast<float2*>(oa + i0) = make_float2(sa0, sa1);
      *reinterpret_cast<float2*>(od + i0) = make_float2(sd0, sd1);
    } else {
      oa[i0] = sa0;
      od[i0] = sd0;
    }
  }
}

// DWT from LDS, 2 outputs/thread
__device__ __forceinline__ void dwt_step(const float* __restrict__ src, int n, int n_out,
                                         float* __restrict__ oa, float* __restrict__ od,
                                         int tid) {
  const int npair = (n_out + 1) / 2;
  for (int t = tid; t < npair; t += NTHR) {
    const int i0 = 2 * t;
    float v[10];
    if (i0 >= 3 && 2 * i0 + 4 <= n) {
      const float2* s2 = reinterpret_cast<const float2*>(src + 2 * i0 - 6);
#pragma unroll
      for (int j = 0; j < 5; ++j) {
        const float2 p = s2[j];
        v[2 * j] = p.x;
        v[2 * j + 1] = p.y;
      }
    } else {
#pragma unroll
      for (int j = 0; j < 10; ++j) {
        const int p = 2 * i0 + j;
        const int q = (p < 6) ? (5 - p) : ((p < n + 6) ? (p - 6) : (2 * n + 5 - p));
        v[j] = src[q];
      }
    }
    float sa0, sd0, sa1, sd1;
    dwt_accum2(v, sa0, sd0, sa1, sd1);
    if (i0 + 1 < n_out) {
      *reinterpret_cast<float2*>(oa + i0) = make_float2(sa0, sa1);
      *reinterpret_cast<float2*>(od + i0) = make_float2(sd0, sd1);
    } else {
      oa[i0] = sa0;
      od[i0] = sd0;
    }
  }
}

// idwt pair: loads c[i0..i0+4], produces out[2i0..2i0+3] as float4.
// i count (n-3) is even for every stage here -> no tails.
template <bool CA, bool CD>
__device__ __forceinline__ void idwt_pair(const float* __restrict__ ca,
                                          const float* __restrict__ cd, int i0,
                                          float4& r) {
  float a[5], d[5];
  if (CA) {
    const float2 u0 = *reinterpret_cast<const float2*>(ca + i0);
    const float2 u1 = *reinterpret_cast<const float2*>(ca + i0 + 2);
    a[0] = u0.x; a[1] = u0.y; a[2] = u1.x; a[3] = u1.y; a[4] = ca[i0 + 4];
  }
  if (CD) {
    const float2 w0 = *reinterpret_cast<const float2*>(cd + i0);
    const float2 w1 = *reinterpret_cast<const float2*>(cd + i0 + 2);
    d[0] = w0.x; d[1] = w0.y; d[2] = w1.x; d[3] = w1.y; d[4] = cd[i0 + 4];
  }
  float e0 = 0.f, o0 = 0.f, e1 = 0.f, o1 = 0.f;
#pragma unroll
  for (int s = 0; s < 4; ++s) {
    const float rl0 = REC_LO[2 * s], rl1 = REC_LO[2 * s + 1];
    const float rh0 = REC_HI[2 * s], rh1 = REC_HI[2 * s + 1];
    if (CA) {
      e0 = fmaf(rl0, a[3 - s], e0);
      o0 = fmaf(rl1, a[3 - s], o0);
      e1 = fmaf(rl0, a[4 - s], e1);
      o1 = fmaf(rl1, a[4 - s], o1);
    }
    if (CD) {
      e0 = fmaf(rh0, d[3 - s], e0);
      o0 = fmaf(rh1, d[3 - s], o0);
      e1 = fmaf(rh0, d[4 - s], e1);
      o1 = fmaf(rh1, d[4 - s], o1);
    }
  }
  r = make_float4(e0, o0, e1, o1);
}

template <bool CA, bool CD>
__device__ __forceinline__ void idwt_lds(const float* __restrict__ ca,
                                         const float* __restrict__ cd, int n,
                                         float* __restrict__ out, int tid) {
  const int npair = (n - 3) / 2;
  float4* out4 = reinterpret_cast<float4*>(out);
  for (int t = tid; t < npair; t += NTHR) {
    float4 r;
    idwt_pair<CA, CD>(ca, cd, 2 * t, r);
    out4[t] = r;
  }
}

template <bool CA, bool CD>
__device__ __forceinline__ void idwt_glob(const float* __restrict__ ca,
                                          const float* __restrict__ cd, int n,
                                          float* __restrict__ out, int tid) {
  const int npair = (n - 3) / 2;
  float4* out4 = reinterpret_cast<float4*>(out);
  for (int t = tid; t < npair; t += NTHR) {
    float4 r;
    idwt_pair<CA, CD>(ca, cd, 2 * t, r);
    out4[t] = r;  // plain store: L2 write-back drains lazily (NT store was +5%)
  }
}

__global__ __launch_bounds__(NTHR, 8) void wavelet_kernel(
    const float* __restrict__ x, float* __restrict__ out_physio,
    float* __restrict__ out_identity) {
  // Aliased LDS: 7520 floats = 30,080 B -> 4 blocks/CU at 512 thr (wave cap 32/CU)
  // A: a1 -> {a3@0, d3@+632, a4@+1264, d4@+1584} -> r3@0 -> r1 -> s1
  // B: d1 (live to the end);  C: a2 -> r2;  D: d2 (live until s1)
  __shared__ __align__(16) float A[2504];
  __shared__ __align__(16) float B[2504];
  __shared__ __align__(16) float C[1256];
  __shared__ __align__(16) float D[1256];

  float* const a3 = A;            // 631 @ A[0..630]
  float* const d3 = A + 632;      // 631 @ A[632..1262]
  float* const a4 = A + 1264;     // 319
  float* const d4 = A + 1584;     // 319 (ends 1902 < 2504)

  const int b = blockIdx.x;
  const int tid = threadIdx.x;
  const float* xrow = x + (size_t)b * NROW;

  // decomposition (level 1 straight from global; x row is L1/L2-resident)
  dwt_glob(xrow, NROW, NB1, A, B, tid);        // a1 -> A, d1 -> B
  __syncthreads();
  dwt_step(A, NB1, NB2, C, D, tid);            // a2 -> C, d2 -> D
  __syncthreads();
  dwt_step(C, NB2, NB3, a3, d3, tid);          // a1 dead: a3/d3 into A
  __syncthreads();
  dwt_step(a3, NB3, NB4, a4, d4, tid);         // reads A[0..630], writes A[1264..] disjoint
  __syncthreads();

  // physio = waverec([a4, d4, d3, 0, 0])
  idwt_lds<true, true>(a4, d4, NB4, A, tid);   // r3 -> A[0..631]
  __syncthreads();
  idwt_lds<true, true>(A, d3, NB3, C, tid);    // r2 -> C
  __syncthreads();
  idwt_lds<true, false>(C, nullptr, NB2, A, tid);  // r1 -> A[0..2503]
  __syncthreads();
  idwt_glob<true, false>(A, nullptr, NB1, out_physio + (size_t)b * NROW, tid);
  __syncthreads();  // A about to be overwritten with s1

  // identity = waverec([0, 0, 0, d2, d1])
  idwt_lds<false, true>(nullptr, D, NB2, A, tid);  // s1 -> A[0..2503]
  __syncthreads();
  idwt_glob<true, true>(A, B, NB1, out_identity + (size_t)b * NROW, tid);
}

extern "C" void kernel_launch(void* const* d_in, const int* in_sizes, int n_in,
                              void* d_out, int out_size, void* d_ws, size_t ws_size,
                              hipStream_t stream) {
  const float* x = (const float*)d_in[0];
  float* out = (float*)d_out;
  const int B = in_sizes[0] / NROW;  // 4096
  wavelet_kernel<<<dim3(B), dim3(NTHR), 0, stream>>>(x, out, out + (size_t)B * NROW);
}

// Round 12
// 46.945 us; speedup vs baseline: 1.2183x; 1.0222x over previous
//
#include <hip/hip_runtime.h>

#define NTHR 512
#define NROW 5000
#define NB1 2503
#define NB2 1255
#define NB3 631
#define NB4 319

// db4 filters (exact values from reference)
__device__ __constant__ float DEC_LO[8] = {
    -0.010597401784997278f, 0.032883011666982945f, 0.030841381835986965f,
    -0.18703481171888114f, -0.02798376941698385f, 0.6308807679295904f,
    0.7148465705525415f, 0.23037781330885523f};
__device__ __constant__ float DEC_HI[8] = {
    -0.23037781330885523f, 0.7148465705525415f, -0.6308807679295904f,
    -0.02798376941698385f, 0.18703481171888114f, 0.030841381835986965f,
    -0.032883011666982945f, -0.010597401784997278f};
__device__ __constant__ float REC_LO[8] = {
    0.23037781330885523f, 0.7148465705525415f, 0.6308807679295904f,
    -0.02798376941698385f, -0.18703481171888114f, 0.030841381835986965f,
    0.032883011666982945f, -0.010597401784997278f};
__device__ __constant__ float REC_HI[8] = {
    -0.010597401784997278f, -0.032883011666982945f, 0.030841381835986965f,
    0.18703481171888114f, -0.02798376941698385f, -0.6308807679295904f,
    0.7148465705525415f, -0.23037781330885523f};

// two adjacent dwt outputs (i0, i0+1) from v[0..9] (taps p = 2*i0 + j)
__device__ __forceinline__ void dwt_accum2(const float v[10], float& sa0, float& sd0,
                                           float& sa1, float& sd1) {
  sa0 = sd0 = sa1 = sd1 = 0.f;
#pragma unroll
  for (int j = 0; j < 8; ++j) {
    const float lo = DEC_LO[7 - j], hi = DEC_HI[7 - j];
    sa0 = fmaf(lo, v[j], sa0);
    sd0 = fmaf(hi, v[j], sd0);
    sa1 = fmaf(lo, v[j + 2], sa1);
    sd1 = fmaf(hi, v[j + 2], sd1);
  }
}

// level-1 DWT reading x from GLOBAL, 2 outputs/thread
__device__ __forceinline__ void dwt_glob(const float* __restrict__ x, int n, int n_out,
                                         float* __restrict__ oa, float* __restrict__ od,
                                         int tid) {
  const int npair = (n_out + 1) / 2;
  for (int t = tid; t < npair; t += NTHR) {
    const int i0 = 2 * t;
    float v[10];
    if (i0 >= 3 && 2 * i0 + 4 <= n) {
      // taps x[2i0-6 .. 2i0+3], interior; 2i0-6 even -> 8B aligned
      const float2* s2 = reinterpret_cast<const float2*>(x + 2 * i0 - 6);
#pragma unroll
      for (int j = 0; j < 5; ++j) {
        const float2 p = s2[j];
        v[2 * j] = p.x;
        v[2 * j + 1] = p.y;
      }
    } else {
#pragma unroll
      for (int j = 0; j < 10; ++j) {
        const int p = 2 * i0 + j;
        const int q = (p < 6) ? (5 - p) : ((p < n + 6) ? (p - 6) : (2 * n + 5 - p));
        v[j] = x[q];
      }
    }
    float sa0, sd0, sa1, sd1;
    dwt_accum2(v, sa0, sd0, sa1, sd1);
    if (i0 + 1 < n_out) {
      *reinterpret_cast<float2*>(oa + i0) = make_float2(sa0, sa1);
      *reinterpret_cast<float2*>(od + i0) = make_float2(sd0, sd1);
    } else {
      oa[i0] = sa0;
      od[i0] = sd0;
    }
  }
}

// DWT from LDS, 2 outputs/thread
__device__ __forceinline__ void dwt_step(const float* __restrict__ src, int n, int n_out,
                                         float* __restrict__ oa, float* __restrict__ od,
                                         int tid) {
  const int npair = (n_out + 1) / 2;
  for (int t = tid; t < npair; t += NTHR) {
    const int i0 = 2 * t;
    float v[10];
    if (i0 >= 3 && 2 * i0 + 4 <= n) {
      const float2* s2 = reinterpret_cast<const float2*>(src + 2 * i0 - 6);
#pragma unroll
      for (int j = 0; j < 5; ++j) {
        const float2 p = s2[j];
        v[2 * j] = p.x;
        v[2 * j + 1] = p.y;
      }
    } else {
#pragma unroll
      for (int j = 0; j < 10; ++j) {
        const int p = 2 * i0 + j;
        const int q = (p < 6) ? (5 - p) : ((p < n + 6) ? (p - 6) : (2 * n + 5 - p));
        v[j] = src[q];
      }
    }
    float sa0, sd0, sa1, sd1;
    dwt_accum2(v, sa0, sd0, sa1, sd1);
    if (i0 + 1 < n_out) {
      *reinterpret_cast<float2*>(oa + i0) = make_float2(sa0, sa1);
      *reinterpret_cast<float2*>(od + i0) = make_float2(sd0, sd1);
    } else {
      oa[i0] = sa0;
      od[i0] = sd0;
    }
  }
}

// idwt pair: loads c[i0..i0+4], produces out[2i0..2i0+3] as float4.
// i count (n-3) is even for every stage here -> no tails.
template <bool CA, bool CD>
__device__ __forceinline__ void idwt_pair(const float* __restrict__ ca,
                                          const float* __restrict__ cd, int i0,
                                          float4& r) {
  float a[5], d[5];
  if (CA) {
    const float2 u0 = *reinterpret_cast<const float2*>(ca + i0);
    const float2 u1 = *reinterpret_cast<const float2*>(ca + i0 + 2);
    a[0] = u0.x; a[1] = u0.y; a[2] = u1.x; a[3] = u1.y; a[4] = ca[i0 + 4];
  }
  if (CD) {
    const float2 w0 = *reinterpret_cast<const float2*>(cd + i0);
    const float2 w1 = *reinterpret_cast<const float2*>(cd + i0 + 2);
    d[0] = w0.x; d[1] = w0.y; d[2] = w1.x; d[3] = w1.y; d[4] = cd[i0 + 4];
  }
  float e0 = 0.f, o0 = 0.f, e1 = 0.f, o1 = 0.f;
#pragma unroll
  for (int s = 0; s < 4; ++s) {
    const float rl0 = REC_LO[2 * s], rl1 = REC_LO[2 * s + 1];
    const float rh0 = REC_HI[2 * s], rh1 = REC_HI[2 * s + 1];
    if (CA) {
      e0 = fmaf(rl0, a[3 - s], e0);
      o0 = fmaf(rl1, a[3 - s], o0);
      e1 = fmaf(rl0, a[4 - s], e1);
      o1 = fmaf(rl1, a[4 - s], o1);
    }
    if (CD) {
      e0 = fmaf(rh0, d[3 - s], e0);
      o0 = fmaf(rh1, d[3 - s], o0);
      e1 = fmaf(rh0, d[4 - s], e1);
      o1 = fmaf(rh1, d[4 - s], o1);
    }
  }
  r = make_float4(e0, o0, e1, o1);
}

template <bool CA, bool CD>
__device__ __forceinline__ void idwt_any(const float* __restrict__ ca,
                                         const float* __restrict__ cd, int n,
                                         float* __restrict__ out, int tid) {
  const int npair = (n - 3) / 2;
  float4* out4 = reinterpret_cast<float4*>(out);
  for (int t = tid; t < npair; t += NTHR) {
    float4 r;
    idwt_pair<CA, CD>(ca, cd, 2 * t, r);
    out4[t] = r;
  }
}

__global__ __launch_bounds__(NTHR, 8) void wavelet_kernel(
    const float* __restrict__ x, float* __restrict__ out_physio,
    float* __restrict__ out_identity) {
  // LDS: 10,024 floats = 40,096 B <= 40,960 B -> still 4 blocks/CU (wave cap 32/CU)
  // A: a1 -> {a3@0, d3@+632, a4@+1264, d4@+1584} -> r3@0 -> r1
  // B: d1 (live to end);  C: a2 -> r2;  D: d2;  E: s1
  __shared__ __align__(16) float A[2504];
  __shared__ __align__(16) float B[2504];
  __shared__ __align__(16) float E[2504];
  __shared__ __align__(16) float C[1256];
  __shared__ __align__(16) float D[1256];

  float* const a3 = A;            // 631 @ A[0..630]
  float* const d3 = A + 632;      // 631 @ A[632..1262]
  float* const a4 = A + 1264;     // 319
  float* const d4 = A + 1584;     // 319 (ends 1902 < 2504)

  const int b = blockIdx.x;
  const int tid = threadIdx.x;
  const float* xrow = x + (size_t)b * NROW;

  // S1: level-1 dwt straight from global (x row is L1/L2-resident)
  dwt_glob(xrow, NROW, NB1, A, B, tid);        // a1 -> A, d1 -> B
  __syncthreads();
  // S2
  dwt_step(A, NB1, NB2, C, D, tid);            // a2 -> C, d2 -> D
  __syncthreads();
  // S3
  dwt_step(C, NB2, NB3, a3, d3, tid);          // a1 dead: a3/d3 into A
  __syncthreads();
  // S4: dwt4 (160 pairs) packed with s1 = idwt(0,d2) (626 pairs) — both underused
  dwt_step(a3, NB3, NB4, a4, d4, tid);         // reads A[0..630], writes A[1264..]
  idwt_any<false, true>(nullptr, D, NB2, E, tid);  // s1 -> E (reads D from S2)
  __syncthreads();
  // S5: physio chain
  idwt_any<true, true>(a4, d4, NB4, A, tid);   // r3 -> A[0..631] (a3 dead)
  __syncthreads();
  // S6
  idwt_any<true, true>(A, d3, NB3, C, tid);    // r2 -> C (a2 dead)
  __syncthreads();
  // S7
  idwt_any<true, false>(C, nullptr, NB2, A, tid);  // r1 -> A[0..2503]
  __syncthreads();
  // S8: both final writes, no barrier between (physio reads A; identity reads E,B)
  idwt_any<true, false>(A, nullptr, NB1, out_physio + (size_t)b * NROW, tid);
  idwt_any<true, true>(E, B, NB1, out_identity + (size_t)b * NROW, tid);
}

extern "C" void kernel_launch(void* const* d_in, const int* in_sizes, int n_in,
                              void* d_out, int out_size, void* d_ws, size_t ws_size,
                              hipStream_t stream) {
  const float* x = (const float*)d_in[0];
  float* out = (float*)d_out;
  const int B = in_sizes[0] / NROW;  // 4096
  wavelet_kernel<<<dim3(B), dim3(NTHR), 0, stream>>>(x, out, out + (size_t)B * NROW);
}